// Round 1
// baseline (774.471 us; speedup 1.0000x reference)
//
#include <hip/hip_runtime.h>
#include <math.h>

// Problem constants (fixed by reference)
#define N_TOT 16384
#define DIM   256
#define KCB   4096

// Tiling
#define BM 32    // rows (ze vectors) per block
#define BN 64    // codebook entries per k-tile
#define BD 128   // d-chunk staged per step

// out layout (floats): [0,N) indices, [N, N+N*D) zq, then e_loss, commit_loss, perplexity
// ws layout (floats):  [0,K) cb_norms; [K,2K) counts; [2K] loss_sum

__global__ void zero_ws_k(float* __restrict__ ws) {
  int i = blockIdx.x * 256 + threadIdx.x;
  if (i < KCB + 1) ws[KCB + i] = 0.0f;   // counts[K] + loss_sum
}

// ||e_k||^2 for each codebook row: one wave per row, 4 elems/lane
__global__ void cbnorm_k(const float* __restrict__ cb, float* __restrict__ ws) {
  int row  = blockIdx.x * 4 + (threadIdx.x >> 6);
  int lane = threadIdx.x & 63;
  float4 v = *(const float4*)(cb + (size_t)row * DIM + lane * 4);
  float s = v.x*v.x + v.y*v.y + v.z*v.z + v.w*v.w;
  #pragma unroll
  for (int off = 32; off > 0; off >>= 1) s += __shfl_down(s, off, 64);
  if (lane == 0) ws[row] = s;
}

__global__ __launch_bounds__(256, 4)
void vq_main_k(const float* __restrict__ ze, const float* __restrict__ cb,
               float* __restrict__ ws, float* __restrict__ out) {
  // LDS: 16KB + 32KB + 2KB + 2KB + 128B ~= 52.3KB -> 3 blocks/CU
  __shared__ float As[BM * BD];
  __shared__ float Bs[BN * BD];
  __shared__ float red_d[BM * 16];
  __shared__ int   red_i[BM * 16];
  __shared__ int   sIdx[BM];

  const int t  = threadIdx.x;
  const int tx = t & 15;   // k-dimension (16 threads x 4 strided k each = 64)
  const int ty = t >> 4;   // row-dimension (16 threads x 2 strided rows = 32)
  const int m0 = blockIdx.x * BM;

  const float* cbn   = ws;
  float* counts      = ws + KCB;
  float* loss_sum    = ws + 2 * KCB;

  float best0 = 1e30f, best1 = 1e30f;
  int   bidx0 = 0,     bidx1 = 0;

  // XOR-swizzle keys (constant per thread): chunk c stored at (c ^ (row&7))
  const int sA = ty & 7;
  const int sB = tx & 7;

  for (int kt = 0; kt < KCB / BN; ++kt) {
    // prefetch codebook norms for this k-tile (L2-hot)
    float cbnj[4];
    #pragma unroll
    for (int j = 0; j < 4; ++j) cbnj[j] = cbn[kt * BN + tx + 16 * j];

    float acc[2][4];
    #pragma unroll
    for (int i = 0; i < 2; ++i)
      #pragma unroll
      for (int j = 0; j < 4; ++j) acc[i][j] = 0.0f;

    for (int dc = 0; dc < DIM / BD; ++dc) {
      __syncthreads();
      { // stage A (32x128) and B (64x128), coalesced global, swizzled LDS
        int c  = t & 31;        // float4 chunk within the 128-float d-chunk
        int rb = t >> 5;        // 8 rows per pass
        #pragma unroll
        for (int p = 0; p < 4; ++p) {
          int r = rb + 8 * p;
          float4 v = *(const float4*)(ze + (size_t)(m0 + r) * DIM + dc * BD + c * 4);
          *(float4*)&As[r * BD + ((c ^ (r & 7)) << 2)] = v;
        }
        #pragma unroll
        for (int p = 0; p < 8; ++p) {
          int r = rb + 8 * p;
          float4 v = *(const float4*)(cb + (size_t)(kt * BN + r) * DIM + dc * BD + c * 4);
          *(float4*)&Bs[r * BD + ((c ^ (r & 7)) << 2)] = v;
        }
      }
      __syncthreads();

      #pragma unroll 8
      for (int ds = 0; ds < BD / 4; ++ds) {
        float4 a0 = *(const float4*)&As[ty * BD + ((ds ^ sA) << 2)];
        float4 a1 = *(const float4*)&As[(ty + 16) * BD + ((ds ^ sA) << 2)];
        float4 b[4];
        #pragma unroll
        for (int j = 0; j < 4; ++j)
          b[j] = *(const float4*)&Bs[(tx + 16 * j) * BD + ((ds ^ sB) << 2)];
        #pragma unroll
        for (int j = 0; j < 4; ++j) {
          acc[0][j] = fmaf(a0.x, b[j].x, acc[0][j]);
          acc[0][j] = fmaf(a0.y, b[j].y, acc[0][j]);
          acc[0][j] = fmaf(a0.z, b[j].z, acc[0][j]);
          acc[0][j] = fmaf(a0.w, b[j].w, acc[0][j]);
          acc[1][j] = fmaf(a1.x, b[j].x, acc[1][j]);
          acc[1][j] = fmaf(a1.y, b[j].y, acc[1][j]);
          acc[1][j] = fmaf(a1.z, b[j].z, acc[1][j]);
          acc[1][j] = fmaf(a1.w, b[j].w, acc[1][j]);
        }
      }
    }

    // distance = ||e||^2 - 2*dot  (||ze||^2 constant per row, argmin-invariant)
    #pragma unroll
    for (int j = 0; j < 4; ++j) {
      int kg = kt * BN + tx + 16 * j;   // ascending k across tiles & j -> '<' keeps first min
      float d0 = cbnj[j] - 2.0f * acc[0][j];
      float d1 = cbnj[j] - 2.0f * acc[1][j];
      if (d0 < best0) { best0 = d0; bidx0 = kg; }
      if (d1 < best1) { best1 = d1; bidx1 = kg; }
    }
  }

  // cross-thread argmin reduce per row (tie -> smaller index, matches np.argmin)
  __syncthreads();
  red_d[ty * 16 + tx] = best0;        red_i[ty * 16 + tx] = bidx0;
  red_d[(ty + 16) * 16 + tx] = best1; red_i[(ty + 16) * 16 + tx] = bidx1;
  __syncthreads();

  if (t < BM) {
    float bd = red_d[t * 16]; int bi = red_i[t * 16];
    #pragma unroll
    for (int q = 1; q < 16; ++q) {
      float d = red_d[t * 16 + q]; int i2 = red_i[t * 16 + q];
      if (d < bd || (d == bd && i2 < bi)) { bd = d; bi = i2; }
    }
    out[m0 + t] = (float)bi;
    sIdx[t] = bi;
    atomicAdd(&counts[bi], 1.0f);
  }
  __syncthreads();

  // zq gather + loss partial: wave w handles rows w,w+4,... lane = d-chunk (coalesced)
  float* out_zq = out + N_TOT;
  const int wv = t >> 6, ln = t & 63;
  float lsum = 0.0f;
  #pragma unroll
  for (int p = 0; p < 8; ++p) {
    int r = wv + 4 * p;
    float4 cv = *(const float4*)(cb + (size_t)sIdx[r] * DIM + ln * 4);
    float4 zv = *(const float4*)(ze + (size_t)(m0 + r) * DIM + ln * 4);
    *(float4*)(out_zq + (size_t)(m0 + r) * DIM + ln * 4) = cv;
    float dx = cv.x - zv.x, dy = cv.y - zv.y, dz = cv.z - zv.z, dw = cv.w - zv.w;
    lsum += dx*dx + dy*dy + dz*dz + dw*dw;
  }
  #pragma unroll
  for (int off = 32; off > 0; off >>= 1) lsum += __shfl_down(lsum, off, 64);
  if (ln == 0) atomicAdd(loss_sum, lsum);
}

__global__ void finalize_k(const float* __restrict__ ws, float* __restrict__ out) {
  __shared__ float red[256];
  int t = threadIdx.x;
  const float* counts = ws + KCB;
  float s = 0.0f;
  for (int k = t; k < KCB; k += 256) {
    float p = counts[k] * 0.1f;              // faithful /10
    s += p * logf(p + 1e-10f);
  }
  red[t] = s;
  __syncthreads();
  for (int q = 128; q > 0; q >>= 1) { if (t < q) red[t] += red[t + q]; __syncthreads(); }
  if (t == 0) {
    float loss = ws[2 * KCB] / (float)((size_t)N_TOT * DIM);
    float* o = out + N_TOT + (size_t)N_TOT * DIM;
    o[0] = loss;          // vq_e_loss
    o[1] = loss;          // vq_commit_loss (numerically identical)
    o[2] = expf(-red[0]); // perplexity (faithfully overflows to +inf)
  }
}

extern "C" void kernel_launch(void* const* d_in, const int* in_sizes, int n_in,
                              void* d_out, int out_size, void* d_ws, size_t ws_size,
                              hipStream_t stream) {
  const float* ze = (const float*)d_in[0];
  const float* cb = (const float*)d_in[1];
  float* out = (float*)d_out;
  float* ws  = (float*)d_ws;

  zero_ws_k<<<(KCB + 1 + 255) / 256, 256, 0, stream>>>(ws);
  cbnorm_k<<<KCB / 4, 256, 0, stream>>>(cb, ws);
  vq_main_k<<<N_TOT / BM, 256, 0, stream>>>(ze, cb, ws, out);
  finalize_k<<<1, 256, 0, stream>>>(ws, out);
}

// Round 2
// 414.869 us; speedup vs baseline: 1.8668x; 1.8668x over previous
//
#include <hip/hip_runtime.h>
#include <math.h>

// Problem constants (fixed by reference)
#define N_TOT 16384
#define DIM   256
#define KCB   4096

typedef __attribute__((ext_vector_type(8)))  short s8v;   // 8 bf16 = 4 VGPR
typedef __attribute__((ext_vector_type(16))) float f16v;  // MFMA 32x32 accumulator

// ---------------- ws layout (bytes) ----------------
// [0)        cbn    : 4096 f32   (||e_k||^2)
// [16384)    counts : 4096 f32
// [32768)    loss   : 1 f32      (pad to 32832)
// [32832)    cbH    : 4096*256 ushort (2 MB)  bf16 hi
// [2129984)  cbL    : 4096*256 ushort (2 MB)  bf16 lo
// total need = 4227136
#define WS_NEED 4227136ull

// out layout (floats): [0,N) indices, [N, N+N*D) zq, then e_loss, commit_loss, perplexity

__global__ void zero_ws_k(float* __restrict__ ws) {
  int i = blockIdx.x * 256 + threadIdx.x;
  if (i < KCB + 1) ws[KCB + i] = 0.0f;   // counts[K] + loss_sum (loss lands at ws[8192])
}

// codebook prep: norms + hi/lo bf16 split. one wave per row, 4 floats/lane.
__global__ void cb_prep_k(const float* __restrict__ cb, float* __restrict__ ws) {
  int row  = blockIdx.x * 4 + (threadIdx.x >> 6);
  int lane = threadIdx.x & 63;
  ushort* cbH = (ushort*)((char*)ws + 32832);
  ushort* cbL = cbH + (size_t)KCB * DIM;
  float4 v = *(const float4*)(cb + (size_t)row * DIM + lane * 4);
  float xs[4] = {v.x, v.y, v.z, v.w};
  unsigned h[4], l[4];
  float s = 0.0f;
  #pragma unroll
  for (int j = 0; j < 4; ++j) {
    s += xs[j] * xs[j];
    unsigned xb = __float_as_uint(xs[j]);
    unsigned hb = xb & 0xFFFF0000u;
    float lf = xs[j] - __uint_as_float(hb);   // exact
    h[j] = hb >> 16;
    l[j] = __float_as_uint(lf) >> 16;          // truncate
  }
  *(uint2*)&cbH[(size_t)row * DIM + lane * 4] = make_uint2(h[0] | (h[1] << 16), h[2] | (h[3] << 16));
  *(uint2*)&cbL[(size_t)row * DIM + lane * 4] = make_uint2(l[0] | (l[1] << 16), l[2] | (l[3] << 16));
  #pragma unroll
  for (int off = 32; off > 0; off >>= 1) s += __shfl_down(s, off, 64);
  if (lane == 0) ws[row] = s;
}

// ---------------- main MFMA kernel ----------------
// 256 blocks x 512 threads (8 waves). Block owns 64 ze rows.
// Each wave: 2 m-tiles (32 rows each) x 32-col strip, sweeps all 4096 cols in
// 16 supertiles of 256 cols (8 waves x 32). A (hi+lo bf16) lives in LDS for the
// whole kernel (padded pitch -> conflict-free-equivalent b128, immediate offsets,
// NO barriers in the K-loop). B streams global->regs (L2-hot).
#define BM 64
#define APITCH 264   // 256 + 8 ushort pad = 528 B row pitch

__global__ __launch_bounds__(512, 2)
void vq_mfma_k(const float* __restrict__ ze, const float* __restrict__ cb,
               float* __restrict__ ws, float* __restrict__ out) {
  __shared__ ushort AhS[BM * APITCH];   // 33 KB
  __shared__ ushort AlS[BM * APITCH];   // 33 KB
  __shared__ float  redS[BM * 8];
  __shared__ int    redI[BM * 8];
  __shared__ int    sIdx[BM];

  const int t  = threadIdx.x;
  const int m0 = blockIdx.x * BM;

  const float* cbn = ws;
  float* counts    = ws + KCB;
  float* loss_sum  = ws + 2 * KCB;
  const ushort* cbH = (const ushort*)((const char*)ws + 32832);
  const ushort* cbL = cbH + (size_t)KCB * DIM;

  // ---- stage A: load fp32 ze rows, split to bf16 h/l, write LDS ----
  {
    int m  = t >> 3;            // 0..63
    int c0 = (t & 7) * 4;       // 4 chunks of 8 floats
    const float* src = ze + (size_t)(m0 + m) * DIM;
    #pragma unroll
    for (int i = 0; i < 4; ++i) {
      int c = c0 + i;
      float4 x0 = *(const float4*)(src + c * 8);
      float4 x1 = *(const float4*)(src + c * 8 + 4);
      float xs[8] = {x0.x, x0.y, x0.z, x0.w, x1.x, x1.y, x1.z, x1.w};
      unsigned h[8], l[8];
      #pragma unroll
      for (int j = 0; j < 8; ++j) {
        unsigned xb = __float_as_uint(xs[j]);
        unsigned hb = xb & 0xFFFF0000u;
        float lf = xs[j] - __uint_as_float(hb);
        h[j] = hb >> 16;
        l[j] = __float_as_uint(lf) >> 16;
      }
      *(uint4*)&AhS[m * APITCH + c * 8] =
          make_uint4(h[0] | (h[1] << 16), h[2] | (h[3] << 16), h[4] | (h[5] << 16), h[6] | (h[7] << 16));
      *(uint4*)&AlS[m * APITCH + c * 8] =
          make_uint4(l[0] | (l[1] << 16), l[2] | (l[3] << 16), l[4] | (l[5] << 16), l[6] | (l[7] << 16));
    }
  }
  __syncthreads();

  const int lane = t & 63;
  const int w    = t >> 6;      // wave 0..7
  const int ln31 = lane & 31;
  const int hl   = lane >> 5;   // half-wave

  // A fragment base pointers (kt-invariant; inner loop uses immediate offsets)
  const ushort* paH0 = AhS + ln31 * APITCH + hl * 8;
  const ushort* paH1 = AhS + (ln31 + 32) * APITCH + hl * 8;
  const ushort* paL0 = AlS + ln31 * APITCH + hl * 8;
  const ushort* paL1 = AlS + (ln31 + 32) * APITCH + hl * 8;

  float best[32];
  int   bidx[32];
  #pragma unroll
  for (int i = 0; i < 32; ++i) { best[i] = -1e30f; bidx[i] = 0; }

  #pragma unroll 1
  for (int kt = 0; kt < 16; ++kt) {
    const int col = kt * 256 + w * 32 + ln31;
    const float cv = cbn[col];
    const s8v* pbh = (const s8v*)(cbH + (size_t)col * DIM + hl * 8);
    const s8v* pbl = (const s8v*)(cbL + (size_t)col * DIM + hl * 8);

    f16v hh0, hh1, xx0, xx1;
    #pragma unroll
    for (int r = 0; r < 16; ++r) {
      hh0[r] = -0.5f * cv; hh1[r] = -0.5f * cv;
      xx0[r] = 0.0f;       xx1[r] = 0.0f;
    }

    s8v bh = pbh[0], bl = pbl[0];
    #pragma unroll
    for (int ks = 0; ks < 16; ++ks) {
      s8v bhn, bln;
      if (ks < 15) { bhn = pbh[2 * ks + 2]; bln = pbl[2 * ks + 2]; }
      s8v ah0 = *(const s8v*)(paH0 + ks * 16);
      s8v ah1 = *(const s8v*)(paH1 + ks * 16);
      s8v al0 = *(const s8v*)(paL0 + ks * 16);
      s8v al1 = *(const s8v*)(paL1 + ks * 16);
      // order chosen to separate same-acc dependent MFMAs
      xx0 = __builtin_amdgcn_mfma_f32_32x32x16_bf16(ah0, bl, xx0, 0, 0, 0);
      xx1 = __builtin_amdgcn_mfma_f32_32x32x16_bf16(ah1, bl, xx1, 0, 0, 0);
      hh0 = __builtin_amdgcn_mfma_f32_32x32x16_bf16(ah0, bh, hh0, 0, 0, 0);
      hh1 = __builtin_amdgcn_mfma_f32_32x32x16_bf16(ah1, bh, hh1, 0, 0, 0);
      xx0 = __builtin_amdgcn_mfma_f32_32x32x16_bf16(al0, bh, xx0, 0, 0, 0);
      xx1 = __builtin_amdgcn_mfma_f32_32x32x16_bf16(al1, bh, xx1, 0, 0, 0);
      if (ks < 15) { bh = bhn; bl = bln; }
    }

    // running argmax of score = dot - 0.5||e||^2  (== argmin distance)
    // kt ascending => cols ascending per slot => strict '>' keeps first min
    #pragma unroll
    for (int r = 0; r < 16; ++r) {
      float s0 = hh0[r] + xx0[r];
      float s1 = hh1[r] + xx1[r];
      if (s0 > best[r])      { best[r]      = s0; bidx[r]      = col; }
      if (s1 > best[16 + r]) { best[16 + r] = s1; bidx[16 + r] = col; }
    }
  }

  // ---- cross-lane argmax: for fixed (tile, reg), all 32 lanes of a half hold
  // the SAME row (row = (r&3)+8*(r>>2)+4*hl), different cols -> butterfly ----
  #pragma unroll
  for (int i = 0; i < 2; ++i) {
    #pragma unroll
    for (int r = 0; r < 16; ++r) {
      float s = best[i * 16 + r];
      int   c = bidx[i * 16 + r];
      #pragma unroll
      for (int mk = 1; mk < 32; mk <<= 1) {
        float os = __shfl_xor(s, mk, 64);
        int   oc = __shfl_xor(c, mk, 64);
        if (os > s || (os == s && oc < c)) { s = os; c = oc; }
      }
      if (ln31 == 0) {
        int row = i * 32 + (r & 3) + 8 * (r >> 2) + 4 * hl;
        redS[row * 8 + w] = s;
        redI[row * 8 + w] = c;
      }
    }
  }
  __syncthreads();

  if (t < BM) {
    float bs = redS[t * 8]; int bi = redI[t * 8];
    #pragma unroll
    for (int j = 1; j < 8; ++j) {
      float s = redS[t * 8 + j]; int c = redI[t * 8 + j];
      if (s > bs || (s == bs && c < bi)) { bs = s; bi = c; }
    }
    out[m0 + t] = (float)bi;
    sIdx[t] = bi;
    atomicAdd(&counts[bi], 1.0f);
  }
  __syncthreads();

  // ---- zq gather + loss partial (fp32 originals; coalesced float4) ----
  float* out_zq = out + N_TOT;
  const int ln = t & 63;
  float lsum = 0.0f;
  #pragma unroll
  for (int p = 0; p < 8; ++p) {
    int r = w + 8 * p;
    float4 cvv = *(const float4*)(cb + (size_t)sIdx[r] * DIM + ln * 4);
    float4 zv  = *(const float4*)(ze + (size_t)(m0 + r) * DIM + ln * 4);
    *(float4*)(out_zq + (size_t)(m0 + r) * DIM + ln * 4) = cvv;
    float dx = cvv.x - zv.x, dy = cvv.y - zv.y, dz = cvv.z - zv.z, dw = cvv.w - zv.w;
    lsum += dx * dx + dy * dy + dz * dz + dw * dw;
  }
  #pragma unroll
  for (int off = 32; off > 0; off >>= 1) lsum += __shfl_down(lsum, off, 64);
  if (ln == 0) atomicAdd(loss_sum, lsum);
}

// ---------------- fallback (round-1 fp32 kernel, used only if ws too small) ----------------
__global__ void cbnorm_k(const float* __restrict__ cb, float* __restrict__ ws) {
  int row  = blockIdx.x * 4 + (threadIdx.x >> 6);
  int lane = threadIdx.x & 63;
  float4 v = *(const float4*)(cb + (size_t)row * DIM + lane * 4);
  float s = v.x*v.x + v.y*v.y + v.z*v.z + v.w*v.w;
  #pragma unroll
  for (int off = 32; off > 0; off >>= 1) s += __shfl_down(s, off, 64);
  if (lane == 0) ws[row] = s;
}

#define FBM 32
#define FBN 64
#define FBD 128
__global__ __launch_bounds__(256, 4)
void vq_main_k(const float* __restrict__ ze, const float* __restrict__ cb,
               float* __restrict__ ws, float* __restrict__ out) {
  __shared__ float As[FBM * FBD];
  __shared__ float Bs[FBN * FBD];
  __shared__ float red_d[FBM * 16];
  __shared__ int   red_i[FBM * 16];
  __shared__ int   sIdx[FBM];

  const int t  = threadIdx.x;
  const int tx = t & 15;
  const int ty = t >> 4;
  const int m0 = blockIdx.x * FBM;

  const float* cbn = ws;
  float* counts    = ws + KCB;
  float* loss_sum  = ws + 2 * KCB;

  float best0 = 1e30f, best1 = 1e30f;
  int   bidx0 = 0,     bidx1 = 0;
  const int sA = ty & 7;
  const int sB = tx & 7;

  for (int kt = 0; kt < KCB / FBN; ++kt) {
    float cbnj[4];
    #pragma unroll
    for (int j = 0; j < 4; ++j) cbnj[j] = cbn[kt * FBN + tx + 16 * j];
    float acc[2][4];
    #pragma unroll
    for (int i = 0; i < 2; ++i)
      #pragma unroll
      for (int j = 0; j < 4; ++j) acc[i][j] = 0.0f;

    for (int dc = 0; dc < DIM / FBD; ++dc) {
      __syncthreads();
      {
        int c  = t & 31;
        int rb = t >> 5;
        #pragma unroll
        for (int p = 0; p < 4; ++p) {
          int r = rb + 8 * p;
          float4 v = *(const float4*)(ze + (size_t)(m0 + r) * DIM + dc * FBD + c * 4);
          *(float4*)&As[r * FBD + ((c ^ (r & 7)) << 2)] = v;
        }
        #pragma unroll
        for (int p = 0; p < 8; ++p) {
          int r = rb + 8 * p;
          float4 v = *(const float4*)(cb + (size_t)(kt * FBN + r) * DIM + dc * FBD + c * 4);
          *(float4*)&Bs[r * FBD + ((c ^ (r & 7)) << 2)] = v;
        }
      }
      __syncthreads();
      #pragma unroll 8
      for (int ds = 0; ds < FBD / 4; ++ds) {
        float4 a0 = *(const float4*)&As[ty * FBD + ((ds ^ sA) << 2)];
        float4 a1 = *(const float4*)&As[(ty + 16) * FBD + ((ds ^ sA) << 2)];
        float4 b[4];
        #pragma unroll
        for (int j = 0; j < 4; ++j)
          b[j] = *(const float4*)&Bs[(tx + 16 * j) * FBD + ((ds ^ sB) << 2)];
        #pragma unroll
        for (int j = 0; j < 4; ++j) {
          acc[0][j] = fmaf(a0.x, b[j].x, acc[0][j]);
          acc[0][j] = fmaf(a0.y, b[j].y, acc[0][j]);
          acc[0][j] = fmaf(a0.z, b[j].z, acc[0][j]);
          acc[0][j] = fmaf(a0.w, b[j].w, acc[0][j]);
          acc[1][j] = fmaf(a1.x, b[j].x, acc[1][j]);
          acc[1][j] = fmaf(a1.y, b[j].y, acc[1][j]);
          acc[1][j] = fmaf(a1.z, b[j].z, acc[1][j]);
          acc[1][j] = fmaf(a1.w, b[j].w, acc[1][j]);
        }
      }
    }
    #pragma unroll
    for (int j = 0; j < 4; ++j) {
      int kg = kt * FBN + tx + 16 * j;
      float d0 = cbnj[j] - 2.0f * acc[0][j];
      float d1 = cbnj[j] - 2.0f * acc[1][j];
      if (d0 < best0) { best0 = d0; bidx0 = kg; }
      if (d1 < best1) { best1 = d1; bidx1 = kg; }
    }
  }

  __syncthreads();
  red_d[ty * 16 + tx] = best0;        red_i[ty * 16 + tx] = bidx0;
  red_d[(ty + 16) * 16 + tx] = best1; red_i[(ty + 16) * 16 + tx] = bidx1;
  __syncthreads();

  if (t < FBM) {
    float bd = red_d[t * 16]; int bi = red_i[t * 16];
    #pragma unroll
    for (int q = 1; q < 16; ++q) {
      float d = red_d[t * 16 + q]; int i2 = red_i[t * 16 + q];
      if (d < bd || (d == bd && i2 < bi)) { bd = d; bi = i2; }
    }
    out[m0 + t] = (float)bi;
    sIdx[t] = bi;
    atomicAdd(&counts[bi], 1.0f);
  }
  __syncthreads();

  float* out_zq = out + N_TOT;
  const int wv = t >> 6, ln = t & 63;
  float lsum = 0.0f;
  #pragma unroll
  for (int p = 0; p < 8; ++p) {
    int r = wv + 4 * p;
    float4 cvv = *(const float4*)(cb + (size_t)sIdx[r] * DIM + ln * 4);
    float4 zv  = *(const float4*)(ze + (size_t)(m0 + r) * DIM + ln * 4);
    *(float4*)(out_zq + (size_t)(m0 + r) * DIM + ln * 4) = cvv;
    float dx = cvv.x - zv.x, dy = cvv.y - zv.y, dz = cvv.z - zv.z, dw = cvv.w - zv.w;
    lsum += dx*dx + dy*dy + dz*dz + dw*dw;
  }
  #pragma unroll
  for (int off = 32; off > 0; off >>= 1) lsum += __shfl_down(lsum, off, 64);
  if (ln == 0) atomicAdd(loss_sum, lsum);
}

__global__ void finalize_k(const float* __restrict__ ws, float* __restrict__ out) {
  __shared__ float red[256];
  int t = threadIdx.x;
  const float* counts = ws + KCB;
  float s = 0.0f;
  for (int k = t; k < KCB; k += 256) {
    float p = counts[k] * 0.1f;
    s += p * logf(p + 1e-10f);
  }
  red[t] = s;
  __syncthreads();
  for (int q = 128; q > 0; q >>= 1) { if (t < q) red[t] += red[t + q]; __syncthreads(); }
  if (t == 0) {
    float loss = ws[2 * KCB] / (float)((size_t)N_TOT * DIM);
    float* o = out + N_TOT + (size_t)N_TOT * DIM;
    o[0] = loss;
    o[1] = loss;
    o[2] = expf(-red[0]);
  }
}

extern "C" void kernel_launch(void* const* d_in, const int* in_sizes, int n_in,
                              void* d_out, int out_size, void* d_ws, size_t ws_size,
                              hipStream_t stream) {
  const float* ze = (const float*)d_in[0];
  const float* cb = (const float*)d_in[1];
  float* out = (float*)d_out;
  float* ws  = (float*)d_ws;

  zero_ws_k<<<(KCB + 1 + 255) / 256, 256, 0, stream>>>(ws);
  if (ws_size >= WS_NEED) {
    cb_prep_k<<<KCB / 4, 256, 0, stream>>>(cb, ws);
    vq_mfma_k<<<N_TOT / BM, 512, 0, stream>>>(ze, cb, ws, out);
  } else {
    cbnorm_k<<<KCB / 4, 256, 0, stream>>>(cb, ws);
    vq_main_k<<<N_TOT / FBM, 256, 0, stream>>>(ze, cb, ws, out);
  }
  finalize_k<<<1, 256, 0, stream>>>(ws, out);
}